// Round 6
// baseline (253.197 us; speedup 1.0000x reference)
//
#include <hip/hip_runtime.h>

// MS-SSIM, 5 levels, 16x3x512x512 fp32, scalar fp32 out.
//
// R6: R4/R5 tiled h/v-pass (s/d channel reduction) with fp16 LDS storage.
//  s = x+y, d = x-y  ==> 4 h-channels (S, D, SS, DD):
//    2*sig12+C2 = (U-V)/2+C2   sig1+sig2+C2 = (U+V)/2+C2
//    2*mu1mu2+C1 = (P-Q)/2+C1  mu1^2+mu2^2+C1 = (P+Q)/2+C1
//  LDS: 4 x fp16 per pixel column (8 B), pitch 33 -> T=64 tile = 19.5 KB
//  -> 8 blocks/CU by LDS at 256 threads, __launch_bounds__(256,8) (VGPR<=64,
//  natural ~52: no spill, unlike R5's (512,8) which forced 32 + scratch).
//  fp16 rounding (RNE) is unbiased; bias on the global mean ~1e-5 << 1e-2.
//  v-pass: ds_read_b64 + fp32 accumulation (mix-fma). Rolling vertical
//  window, thread = 1 col x OPT rows. Downsample for next level fused.

#define NSLOT 32

typedef float v4  __attribute__((ext_vector_type(4)));
typedef float v2f __attribute__((ext_vector_type(2)));
typedef _Float16 h4 __attribute__((ext_vector_type(4)));

__device__ __forceinline__ float frcp(float x) { return __builtin_amdgcn_rcpf(x); }

template<int TROWS, int NTHR, int MINW>
__global__ __launch_bounds__(NTHR, MINW) void ssim_tile_kernel(
    const float* __restrict__ img1, const float* __restrict__ img2,
    float* __restrict__ ds1, float* __restrict__ ds2,
    int H, int do_ds, float* __restrict__ acc)
{
    constexpr int HR    = TROWS + 10;          // h-rows per tile
    constexpr int OPT   = TROWS * 32 / NTHR;   // output rows per thread
    constexpr int PITCH = 33;                  // pixels per LDS row (32+1 pad)
    constexpr int NW    = NTHR / 64;           // waves per block

    const float GW[11] = {0.00102840f, 0.00759877f, 0.03600070f, 0.10936069f,
                          0.21300636f, 0.26601172f, 0.21300636f, 0.10936069f,
                          0.03600070f, 0.00759877f, 0.00102840f};
    const float C1 = 1e-4f, C2 = 9e-4f;

    __shared__ h4 hb[HR * PITCH];
    __shared__ float red[2 * NW];

    const int tid  = threadIdx.x;
    const int nc   = blockIdx.z;
    const int tx0  = blockIdx.x * 32;
    const int ty0  = blockIdx.y * TROWS;
    const int outHW = H - 10;
    const float* p1 = img1 + (size_t)nc * H * H;
    const float* p2 = img2 + (size_t)nc * H * H;

    // ---- fused 2x2 avg-pool of the block's core region (independent work)
    if (do_ds) {
        const int H2 = H >> 1;
        #pragma unroll
        for (int t = tid; t < 16 * (TROWS / 2); t += NTHR) {
            int r = t >> 4, cdd = t & 15;
            int iy = ty0 + 2 * r, ix = tx0 + 2 * cdd;
            if (iy + 1 < H) {
                v2f a0 = *(const v2f*)(p1 + (size_t)iy * H + ix);
                v2f a1 = *(const v2f*)(p1 + (size_t)(iy + 1) * H + ix);
                v2f b0 = *(const v2f*)(p2 + (size_t)iy * H + ix);
                v2f b1 = *(const v2f*)(p2 + (size_t)(iy + 1) * H + ix);
                size_t o = (size_t)nc * H2 * H2
                         + (size_t)((ty0 >> 1) + r) * H2 + ((tx0 >> 1) + cdd);
                ds1[o] = 0.25f * ((a0.x + a0.y) + (a1.x + a1.y));
                ds2[o] = 0.25f * ((b0.x + b0.y) + (b1.x + b1.y));
            }
        }
    }

    // ---- horizontal pass: HR rows x 8 col-groups (4 cols each)
    for (int task = tid; task < HR * 8; task += NTHR) {
        const int r  = task >> 3, cg = task & 7;
        const int gr = ty0 + r;
        const int c0 = tx0 + cg * 4;
        v4 hs = 0.f, hd = 0.f, hss = 0.f, hdd = 0.f;
        if (gr < H) {
            float s[16], d[16];
            if (c0 + 16 <= H) {
                const float* pa = p1 + (size_t)gr * H + c0;
                const float* pb = p2 + (size_t)gr * H + c0;
                #pragma unroll
                for (int q = 0; q < 4; ++q) {
                    v4 va = *(const v4*)(pa + 4 * q);
                    v4 vb = *(const v4*)(pb + 4 * q);
                    v4 sv = va + vb, dv = va - vb;
                    s[4*q+0] = sv.x; s[4*q+1] = sv.y; s[4*q+2] = sv.z; s[4*q+3] = sv.w;
                    d[4*q+0] = dv.x; d[4*q+1] = dv.y; d[4*q+2] = dv.z; d[4*q+3] = dv.w;
                }
            } else {
                #pragma unroll
                for (int q = 0; q < 16; ++q) {
                    int cc = c0 + q;
                    float a = (cc < H) ? p1[(size_t)gr * H + cc] : 0.f;
                    float b = (cc < H) ? p2[(size_t)gr * H + cc] : 0.f;
                    s[q] = a + b; d[q] = a - b;
                }
            }
            #pragma unroll
            for (int j = 0; j < 11; ++j) {
                float w = GW[j];
                v4 sv = {s[j], s[j+1], s[j+2], s[j+3]};
                v4 dv = {d[j], d[j+1], d[j+2], d[j+3]};
                v4 ws = w * sv, wd = w * dv;
                hs += ws; hd += wd; hss += ws * sv; hdd += wd * dv;
            }
        }
        h4* row = &hb[r * PITCH + cg * 4];
        row[0] = (h4){(_Float16)hs.x, (_Float16)hd.x, (_Float16)hss.x, (_Float16)hdd.x};
        row[1] = (h4){(_Float16)hs.y, (_Float16)hd.y, (_Float16)hss.y, (_Float16)hdd.y};
        row[2] = (h4){(_Float16)hs.z, (_Float16)hd.z, (_Float16)hss.z, (_Float16)hdd.z};
        row[3] = (h4){(_Float16)hs.w, (_Float16)hd.w, (_Float16)hss.w, (_Float16)hdd.w};
    }
    __syncthreads();

    // ---- vertical pass + ssim/cs: thread = 1 column x OPT rows (rolling)
    const int col  = tid & 31;
    const int row0 = (tid >> 5) * OPT;
    const float colm = (tx0 + col < outHW) ? 1.f : 0.f;
    v4 A[OPT];
    #pragma unroll
    for (int k = 0; k < OPT; ++k) A[k] = 0.f;

    #pragma unroll
    for (int r = 0; r < OPT + 10; ++r) {
        h4 h = hb[(row0 + r) * PITCH + col];
        v4 f = {(float)h.x, (float)h.y, (float)h.z, (float)h.w};
        #pragma unroll
        for (int k = 0; k < OPT; ++k) {
            const int j = r - k;
            if (j >= 0 && j < 11) A[k] += GW[j] * f;
        }
    }

    float ssim_t = 0.f, cs_t = 0.f;
    #pragma unroll
    for (int k = 0; k < OPT; ++k) {
        float mask = colm * ((ty0 + row0 + k < outHW) ? 1.f : 0.f);
        float mu_s = A[k].x, mu_d = A[k].y;
        float P = mu_s * mu_s, Q = mu_d * mu_d;
        float U = A[k].z - P, V = A[k].w - Q;
        float v1 = 0.5f * (U - V) + C2;
        float v2 = 0.5f * (U + V) + C2;
        float n1 = 0.5f * (P - Q) + C1;
        float d1 = 0.5f * (P + Q) + C1;
        float csv = v1 * frcp(v2);
        float ssv = n1 * csv * frcp(d1);
        cs_t   += mask * csv;
        ssim_t += mask * ssv;
    }

    // ---- block reduction + spread atomics
    #pragma unroll
    for (int off = 32; off > 0; off >>= 1) {
        ssim_t += __shfl_down(ssim_t, off);
        cs_t   += __shfl_down(cs_t, off);
    }
    int wave = tid >> 6, lane = tid & 63;
    if (lane == 0) { red[wave] = ssim_t; red[NW + wave] = cs_t; }
    __syncthreads();
    if (tid == 0) {
        float s = 0.f, c2s = 0.f;
        #pragma unroll
        for (int w = 0; w < NW; ++w) { s += red[w]; c2s += red[NW + w]; }
        int slot = (blockIdx.x + blockIdx.y * 5 + blockIdx.z * 11) & (NSLOT - 1);
        atomicAdd(&acc[slot], s);
        atomicAdd(&acc[NSLOT + slot], c2s);
    }
}

__global__ void finalize_kernel(const float* __restrict__ acc, float* __restrict__ out)
{
    if (threadIdx.x == 0 && blockIdx.x == 0) {
        const float w[5] = {0.0448f, 0.2856f, 0.3001f, 0.2363f, 0.1333f};
        float ms[5], mc[5];
        for (int l = 0; l < 5; ++l) {
            float s = 0.f, c = 0.f;
            for (int k = 0; k < NSLOT; ++k) {
                s += acc[2 * NSLOT * l + k];
                c += acc[2 * NSLOT * l + NSLOT + k];
            }
            int oh = (512 >> l) - 10;
            float cnt = 48.f * (float)oh * (float)oh;
            ms[l] = (s / cnt + 1.f) * 0.5f;
            mc[l] = (c / cnt + 1.f) * 0.5f;
        }
        float p2 = powf(ms[4], w[4]);
        float r = 1.f;
        for (int i = 0; i < 4; ++i) r *= powf(mc[i], w[i]) * p2;
        out[0] = r;
    }
}

extern "C" void kernel_launch(void* const* d_in, const int* in_sizes, int n_in,
                              void* d_out, int out_size, void* d_ws, size_t ws_size,
                              hipStream_t stream)
{
    const float* img1 = (const float*)d_in[0];
    const float* img2 = (const float*)d_in[1];
    float* out = (float*)d_out;
    float* ws  = (float*)d_ws;

    float* acc = ws;              // 5 levels x 2 x NSLOT floats
    size_t off = 512;

    const float* buf1[5];
    const float* buf2[5];
    float* wbuf1[5];
    float* wbuf2[5];
    buf1[0] = img1; buf2[0] = img2;
    for (int l = 1; l < 5; ++l) {
        int Hl = 512 >> l;
        size_t sz = (size_t)48 * Hl * Hl;
        wbuf1[l] = ws + off; off += sz;
        wbuf2[l] = ws + off; off += sz;
        buf1[l] = wbuf1[l];
        buf2[l] = wbuf2[l];
    }

    hipMemsetAsync(acc, 0, 5 * 2 * NSLOT * sizeof(float), stream);

    const int Hs[5] = {512, 256, 128, 64, 32};
    const int Ts[5] = {64, 64, 32, 16, 16};

    for (int l = 0; l < 5; ++l) {
        int H = Hs[l], T = Ts[l];
        int outH = H - 10;
        int ctiles = (outH + 31) / 32;
        int rtiles = (outH + T - 1) / T;
        dim3 grid(ctiles, rtiles, 48);
        float* d1 = l < 4 ? wbuf1[l + 1] : nullptr;
        float* d2 = l < 4 ? wbuf2[l + 1] : nullptr;
        int dd = l < 4 ? 1 : 0;
        float* a = acc + 2 * NSLOT * l;
        if (T == 64)
            ssim_tile_kernel<64, 256, 8><<<grid, 256, 0, stream>>>(buf1[l], buf2[l], d1, d2, H, dd, a);
        else if (T == 32)
            ssim_tile_kernel<32, 256, 8><<<grid, 256, 0, stream>>>(buf1[l], buf2[l], d1, d2, H, dd, a);
        else
            ssim_tile_kernel<16, 256, 8><<<grid, 256, 0, stream>>>(buf1[l], buf2[l], d1, d2, H, dd, a);
    }

    finalize_kernel<<<1, 64, 0, stream>>>(acc, out);
}